// Round 1
// baseline (220.977 us; speedup 1.0000x reference)
//
#include <hip/hip_runtime.h>

typedef __attribute__((ext_vector_type(4))) float f32x4;
typedef __attribute__((ext_vector_type(8))) short short8;
typedef __attribute__((ext_vector_type(4))) short short4v;
typedef __attribute__((ext_vector_type(4))) unsigned short ushort4v;
typedef __attribute__((ext_vector_type(8))) unsigned short ushort8v;

#define B_ROWS 4096
#define I_DIM  1024
#define O_DIM  1024
#define C_DIM  128
#define E_NUM  8

// ws layout: [0] int flag | [1024] float g[4096*8] | [1024+131072] u16 Wt[8*1024*1024]

__device__ __forceinline__ float bfu2f(unsigned short u) {
  return __uint_as_float(((unsigned int)u) << 16);
}
__device__ __forceinline__ unsigned short f2bf(float f) {
  unsigned int u = __float_as_uint(f);
  unsigned int r = (u + 0x7FFFu + ((u >> 16) & 1u)) >> 16;  // RNE
  return (unsigned short)r;
}
__device__ __forceinline__ float ldany(const void* p, size_t idx, bool isbf) {
  return isbf ? bfu2f(((const unsigned short*)p)[idx]) : ((const float*)p)[idx];
}
__device__ __forceinline__ void gload_lds16(const void* g, void* lds) {
  __builtin_amdgcn_global_load_lds(
      (const __attribute__((address_space(1))) void*)g,
      (__attribute__((address_space(3))) void*)lds, 16, 0, 0);
}

// ---------------- dtype detect: bf16 storage -> flag=1, f32 -> flag=0 -------
__global__ void k_detect(const unsigned short* __restrict__ x, int* __restrict__ flag) {
  if (blockIdx.x == 0 && threadIdx.x == 0) {
    int sane = 0;
    for (int k = 0; k < 128; ++k) {
      const unsigned short v = x[k];
      const int ex = (v >> 7) & 0xFF;
      if (v == 0 || (ex >= 100 && ex <= 132)) ++sane;
    }
    // bf16(N(0,1)) stream: ~128/128 sane. f32 stream: ~72/128 sane.
    *flag = (sane >= 120) ? 1 : 0;
  }
}

// ---------------- gating MLP + softmax, one thread per row ------------------
__global__ __launch_bounds__(256) void k_gating(
    const void* __restrict__ cond, const void* __restrict__ w1,
    const void* __restrict__ b1, const void* __restrict__ w2,
    const void* __restrict__ b2, const int* __restrict__ flag,
    float* __restrict__ g)
{
  __shared__ float s_w1[C_DIM * 32];
  __shared__ float s_w2[32 * E_NUM];
  __shared__ float s_b1[32];
  __shared__ float s_b2[E_NUM];
  const bool isbf = (*flag != 0);
  for (int t = threadIdx.x; t < C_DIM * 32; t += 256) s_w1[t] = ldany(w1, t, isbf);
  if (threadIdx.x < 32 * E_NUM) s_w2[threadIdx.x] = ldany(w2, threadIdx.x, isbf);
  if (threadIdx.x < 32) s_b1[threadIdx.x] = ldany(b1, threadIdx.x, isbf);
  if (threadIdx.x < E_NUM) s_b2[threadIdx.x] = ldany(b2, threadIdx.x, isbf);
  __syncthreads();
  const int b = blockIdx.x * 256 + threadIdx.x;
  float h[32];
#pragma unroll
  for (int j = 0; j < 32; ++j) h[j] = s_b1[j];
  for (int i = 0; i < C_DIM; i += 8) {
    float c[8];
    if (isbf) {
      const unsigned short* cu = (const unsigned short*)cond;
      ushort8v v = *(const ushort8v*)&cu[(size_t)b * C_DIM + i];
#pragma unroll
      for (int q = 0; q < 8; ++q) c[q] = bfu2f(v[q]);
    } else {
      const float* cf = (const float*)cond;
      f32x4 v0 = *(const f32x4*)&cf[(size_t)b * C_DIM + i];
      f32x4 v1 = *(const f32x4*)&cf[(size_t)b * C_DIM + i + 4];
#pragma unroll
      for (int q = 0; q < 4; ++q) { c[q] = v0[q]; c[q + 4] = v1[q]; }
    }
#pragma unroll
    for (int q = 0; q < 8; ++q)
#pragma unroll
      for (int j = 0; j < 32; ++j)
        h[j] = fmaf(c[q], s_w1[(i + q) * 32 + j], h[j]);
  }
#pragma unroll
  for (int j = 0; j < 32; ++j) h[j] = fmaxf(h[j], 0.f);
  float lg[E_NUM];
#pragma unroll
  for (int e = 0; e < E_NUM; ++e) lg[e] = s_b2[e];
#pragma unroll
  for (int j = 0; j < 32; ++j)
#pragma unroll
    for (int e = 0; e < E_NUM; ++e)
      lg[e] = fmaf(h[j], s_w2[j * E_NUM + e], lg[e]);
  float mx = lg[0];
#pragma unroll
  for (int e = 1; e < E_NUM; ++e) mx = fmaxf(mx, lg[e]);
  float s = 0.f;
#pragma unroll
  for (int e = 0; e < E_NUM; ++e) { lg[e] = expf(lg[e] - mx); s += lg[e]; }
  const float inv = 1.f / s;
#pragma unroll
  for (int e = 0; e < E_NUM; ++e) g[(size_t)b * E_NUM + e] = lg[e] * inv;
}

// ---------------- W[e][i][o] -> Wt[e][o][i] (bf16), 64x64 tiles -------------
__global__ __launch_bounds__(256) void k_transpose_w(
    const void* __restrict__ wv, const int* __restrict__ flag,
    unsigned short* __restrict__ wt)
{
  __shared__ float tile[64][65];
  const bool isbf = (*flag != 0);
  const int bid = blockIdx.x;
  const int e = bid >> 8;
  const int t = bid & 255;
  const int i0 = (t >> 4) << 6;
  const int o0 = (t & 15) << 6;
  const size_t base = (size_t)e << 20;
  const int tid = threadIdx.x;
  const int r = tid >> 2;
  const int sub = tid & 3;
  if (isbf) {
    const unsigned short* wu = (const unsigned short*)wv;
#pragma unroll
    for (int q = 0; q < 4; ++q) {
      const int c = sub * 16 + q * 4;
      ushort4v v = *(const ushort4v*)&wu[base + (size_t)(i0 + r) * O_DIM + o0 + c];
#pragma unroll
      for (int j = 0; j < 4; ++j) tile[r][c + j] = bfu2f(v[j]);
    }
  } else {
    const float* wf = (const float*)wv;
#pragma unroll
    for (int q = 0; q < 4; ++q) {
      const int c = sub * 16 + q * 4;
      f32x4 v = *(const f32x4*)&wf[base + (size_t)(i0 + r) * O_DIM + o0 + c];
#pragma unroll
      for (int j = 0; j < 4; ++j) tile[r][c + j] = v[j];
    }
  }
  __syncthreads();
  const int oc = tid >> 2;
#pragma unroll
  for (int q = 0; q < 4; ++q) {
    const int il = sub * 16 + q * 4;
    ushort4v p;
#pragma unroll
    for (int j = 0; j < 4; ++j) p[j] = f2bf(tile[il + j][oc]);
    *(ushort4v*)&wt[base + (size_t)(o0 + oc) * I_DIM + i0 + il] = p;
  }
}

// ---------------- main GEMM: out = sum_e g[:,e] * (x @ W_e) + g @ bias ------
// BM=64 x BN=128 tile, BK=64, 4 waves (2x2), 512 blocks. Dual accumulator:
// seg accumulates x@W_e for the current expert; folded into acc with the
// per-row gate at each expert boundary (16 K-tiles).
#define BM 64
#define BN 128
#define BK 64

__global__ __launch_bounds__(256, 2) void k_moe_gemm(
    const void* __restrict__ xv, const unsigned short* __restrict__ wt,
    const void* __restrict__ biasv, const float* __restrict__ g,
    const int* __restrict__ flag, void* __restrict__ outv)
{
  __shared__ unsigned short As[BM * BK];   // [64 rows][64 k] 8KB, k-contig
  __shared__ unsigned short Bs[BN * BK];   // [128 cols][64 k] 16KB, k-contig
  __shared__ float gs[BM * E_NUM];         // 2KB

  const int tid  = threadIdx.x;
  const int lane = tid & 63;
  const int wid  = tid >> 6;
  const int wr   = wid >> 1;       // wave row (0..1), 32 rows each
  const int wc   = wid & 1;        // wave col (0..1), 64 cols each
  const int bid  = blockIdx.x;
  const int mt   = bid >> 3;       // 64 M-tiles
  const int nt   = bid & 7;        // 8 N-tiles
  const int row0 = mt * BM;
  const int col0 = nt * BN;
  const bool isbf = (*flag != 0);

  for (int t = tid; t < BM * E_NUM; t += 256) gs[t] = g[row0 * E_NUM + t];

  f32x4 acc[2][4], seg[2][4];
#pragma unroll
  for (int m = 0; m < 2; ++m)
#pragma unroll
    for (int n = 0; n < 4; ++n)
#pragma unroll
      for (int r2 = 0; r2 < 4; ++r2) { acc[m][n][r2] = 0.f; seg[m][n][r2] = 0.f; }

  const int r16  = lane & 15;
  const int krow = lane >> 4;

  for (int e = 0; e < E_NUM; ++e) {
    const size_t wb = ((size_t)e << 20);
    for (int kt = 0; kt < I_DIM; kt += BK) {
      __syncthreads();
      // stage B tile (always bf16 from Wt): 16 chunks of 1KB, 4 per wave
#pragma unroll
      for (int q = 0; q < 4; ++q) {
        const int off = ((wid * 4 + q) << 10) + (lane << 4);
        const int n   = off >> 7;
        const int kb  = off & 127;
        const unsigned short* gp = wt + wb + (size_t)(col0 + n) * I_DIM + kt + (kb >> 1);
        gload_lds16(gp, (char*)Bs + ((wid * 4 + q) << 10));
      }
      // stage A tile
      if (isbf) {
        const unsigned short* xu = (const unsigned short*)xv;
#pragma unroll
        for (int q = 0; q < 2; ++q) {
          const int off = ((wid * 2 + q) << 10) + (lane << 4);
          const int r   = off >> 7;
          const int kb  = off & 127;
          const unsigned short* gp = xu + (size_t)(row0 + r) * I_DIM + kt + (kb >> 1);
          gload_lds16(gp, (char*)As + ((wid * 2 + q) << 10));
        }
      } else {
        const float* xf = (const float*)xv;
        const int r  = tid >> 2;
        const int k0 = (tid & 3) << 4;
#pragma unroll
        for (int q = 0; q < 4; ++q) {
          f32x4 v = *(const f32x4*)&xf[(size_t)(row0 + r) * I_DIM + kt + k0 + q * 4];
          short4v p;
#pragma unroll
          for (int j = 0; j < 4; ++j) p[j] = (short)f2bf(v[j]);
          *(short4v*)&As[r * BK + k0 + q * 4] = p;
        }
      }
      __syncthreads();
      // compute: 2 k-steps of 32, 8 MFMAs each
#pragma unroll
      for (int ks = 0; ks < 2; ++ks) {
        const int kof = ks * 32 + krow * 8;
        short8 a[2], b[4];
#pragma unroll
        for (int m = 0; m < 2; ++m)
          a[m] = *(const short8*)&As[(wr * 32 + m * 16 + r16) * BK + kof];
#pragma unroll
        for (int n = 0; n < 4; ++n)
          b[n] = *(const short8*)&Bs[(wc * 64 + n * 16 + r16) * BK + kof];
#pragma unroll
        for (int m = 0; m < 2; ++m)
#pragma unroll
          for (int n = 0; n < 4; ++n)
            seg[m][n] = __builtin_amdgcn_mfma_f32_16x16x32_bf16(a[m], b[n], seg[m][n], 0, 0, 0);
      }
    }
    // fold expert e: acc += g[row, e] * seg; C/D row = krow*4 + reg (m89/m91)
#pragma unroll
    for (int m = 0; m < 2; ++m) {
      const int rb = wr * 32 + m * 16 + krow * 4;
      float gv[4];
#pragma unroll
      for (int r2 = 0; r2 < 4; ++r2) gv[r2] = gs[(rb + r2) * E_NUM + e];
#pragma unroll
      for (int n = 0; n < 4; ++n)
#pragma unroll
        for (int r2 = 0; r2 < 4; ++r2) {
          acc[m][n][r2] += gv[r2] * seg[m][n][r2];
          seg[m][n][r2] = 0.f;
        }
    }
  }

  // epilogue: add bias term sum_e g[r,e]*bias[e,c], write out
#pragma unroll
  for (int n = 0; n < 4; ++n) {
    const int c = col0 + wc * 64 + n * 16 + r16;
    float bb[E_NUM];
#pragma unroll
    for (int e2 = 0; e2 < E_NUM; ++e2)
      bb[e2] = ldany(biasv, (size_t)e2 * O_DIM + c, isbf);
#pragma unroll
    for (int m = 0; m < 2; ++m) {
      const int rl = wr * 32 + m * 16 + krow * 4;
#pragma unroll
      for (int r2 = 0; r2 < 4; ++r2) {
        float bt = 0.f;
#pragma unroll
        for (int e2 = 0; e2 < E_NUM; ++e2) bt += gs[(rl + r2) * E_NUM + e2] * bb[e2];
        const float v = acc[m][n][r2] + bt;
        const size_t idx = (size_t)(row0 + rl + r2) * O_DIM + c;
        if (isbf) ((unsigned short*)outv)[idx] = f2bf(v);
        else      ((float*)outv)[idx] = v;
      }
    }
  }
}

extern "C" void kernel_launch(void* const* d_in, const int* in_sizes, int n_in,
                              void* d_out, int out_size, void* d_ws, size_t ws_size,
                              hipStream_t stream) {
  (void)in_sizes; (void)n_in; (void)out_size; (void)ws_size;
  const void* x    = d_in[0];
  const void* cond = d_in[1];
  const void* w    = d_in[2];
  const void* bias = d_in[3];
  const void* g_w1 = d_in[4];
  const void* g_b1 = d_in[5];
  const void* g_w2 = d_in[6];
  const void* g_b2 = d_in[7];
  int*   flag = (int*)d_ws;
  float* g    = (float*)((char*)d_ws + 1024);
  unsigned short* wt = (unsigned short*)((char*)d_ws + 1024 + (size_t)B_ROWS * E_NUM * 4);

  k_detect<<<1, 64, 0, stream>>>((const unsigned short*)x, flag);
  k_gating<<<B_ROWS / 256, 256, 0, stream>>>(cond, g_w1, g_b1, g_w2, g_b2, flag, g);
  k_transpose_w<<<E_NUM * 256, 256, 0, stream>>>(w, flag, wt);
  k_moe_gemm<<<(B_ROWS / BM) * (O_DIM / BN), 256, 0, stream>>>(x, wt, bias, g, flag, d_out);
}